// Round 2
// baseline (245.715 us; speedup 1.0000x reference)
//
#include <hip/hip_runtime.h>
#include <cfloat>
#include <cstdint>

#define NSEG 512
#define C 21

// ---- NN pass-1 config ----
#define K1_THREADS 512
#define QT 4                      // queries per thread
#define QPB (K1_THREADS * QT)     // 2048 queries per block
#define PPB 1024                  // points per block tile
#define EPS_FLAG 2e-4f            // >= 3x worst-case f32 rounding error of the distance chain

// K1: f32, INDEX-FREE partial scan. For each (query-chunk, point-chunk) track the two
// smallest values of v = |p|^2 - 2 q.p (|q|^2 constant per query -> argmin-invariant).
// 12 cy/pair on the VALU: 3 fma + min + max + min. Indices recovered later.
__global__ __launch_bounds__(K1_THREADS)
void nn_partial(const float* __restrict__ pts, const float* __restrict__ dpts,
                int n, int m, float2* __restrict__ pb) {
    __shared__ float4 lp[PPB];
    const int qc = blockIdx.x, pc = blockIdx.y;
    const int t = threadIdx.x;
    const int pbase = pc * PPB;

    for (int j = t; j < PPB; j += K1_THREADS) {
        int p = pbase + j;
        float4 v = make_float4(0.f, 0.f, 0.f, FLT_MAX);
        if (p < n) {
            float x = pts[p * 3 + 0], y = pts[p * 3 + 1], z = pts[p * 3 + 2];
            v = make_float4(x, y, z, fmaf(x, x, fmaf(y, y, z * z)));
        }
        lp[j] = v;
    }
    __syncthreads();

    float m2x[QT], m2y[QT], m2z[QT], b1[QT], b2[QT];
    int qv[QT];
#pragma unroll
    for (int k = 0; k < QT; k++) {
        int qi = qc * QPB + t + k * K1_THREADS;
        qv[k] = qi;
        float qx = 0.f, qy = 0.f, qz = 0.f;
        if (qi < m) {
            qx = dpts[qi * 3 + 0]; qy = dpts[qi * 3 + 1]; qz = dpts[qi * 3 + 2];
        }
        m2x[k] = -2.f * qx; m2y[k] = -2.f * qy; m2z[k] = -2.f * qz;  // exact in f32
        b1[k] = FLT_MAX; b2[k] = FLT_MAX;
    }

#pragma unroll 4
    for (int j = 0; j < PPB; j++) {
        float4 p = lp[j];
#pragma unroll
        for (int k = 0; k < QT; k++) {
            float v = fmaf(p.x, m2x[k], fmaf(p.y, m2y[k], fmaf(p.z, m2z[k], p.w)));
            float t2 = fmaxf(v, b1[k]);          // old b1
            b1[k] = fminf(b1[k], v);
            b2[k] = fminf(b2[k], t2);
        }
    }

#pragma unroll
    for (int k = 0; k < QT; k++)
        if (qv[k] < m) pb[(size_t)pc * m + qv[k]] = make_float2(b1[k], b2[k]);
}

// K2: merge chunk (b1,b2) pairs -> global (g1,g2,winner_chunk).
// Flag ambiguous queries (gap <= EPS) for exact f64 resolution.
__global__ __launch_bounds__(256)
void nn_reduce(const float2* __restrict__ pb, int m, int PC,
               int* __restrict__ wchunk, float* __restrict__ gmin,
               int* __restrict__ flagged, int* __restrict__ nflag) {
    int q = blockIdx.x * 256 + threadIdx.x;
    if (q >= m) return;
    float g1 = FLT_MAX, g2 = FLT_MAX; int wc = 0;
    for (int pc = 0; pc < PC; pc++) {
        float2 c = pb[(size_t)pc * m + q];
        float n1 = fminf(g1, c.x);
        float n2 = fminf(fmaxf(g1, c.x), fminf(g2, c.y));  // exact global 2nd-best
        if (c.x < g1) wc = pc;                             // strict <: first chunk wins
        g1 = n1; g2 = n2;
    }
    if (g2 - g1 <= EPS_FLAG) {       // near-tie (incl. exact f32 ties) -> f64 path
        int slot = atomicAdd(nflag, 1);
        flagged[slot] = q;
        wchunk[q] = -1;
    } else {
        wchunk[q] = wc;
        gmin[q] = g1;
    }
}

// K3: index recovery for unflagged queries: rescan the 1024-point winner chunk with the
// BITWISE-identical f32 formula; the first j with v == g1 is the argmin (unique, else flagged).
__global__ __launch_bounds__(256)
void nn_recover(const float* __restrict__ pts, const float* __restrict__ dpts,
                const int* __restrict__ wchunk, const float* __restrict__ gmin,
                int m, int* __restrict__ nn_idx,
                int* __restrict__ flagged, int* __restrict__ nflag) {
    int q = blockIdx.x * 4 + (threadIdx.x >> 6);
    int lane = threadIdx.x & 63;
    if (q >= m) return;
    int wc = wchunk[q];
    if (wc < 0) return;
    float b1v = gmin[q];
    float m2x = -2.f * dpts[q * 3 + 0];
    float m2y = -2.f * dpts[q * 3 + 1];
    float m2z = -2.f * dpts[q * 3 + 2];
    int pbase = wc * PPB;
    int cand = 0x7fffffff;
#pragma unroll 4
    for (int it = 0; it < PPB / 64; it++) {
        int j = pbase + lane + it * 64;
        float x = pts[j * 3 + 0], y = pts[j * 3 + 1], z = pts[j * 3 + 2];
        float w = fmaf(x, x, fmaf(y, y, z * z));
        float v = fmaf(x, m2x, fmaf(y, m2y, fmaf(z, m2z, w)));
        if (v == b1v) cand = min(cand, j);
    }
#pragma unroll
    for (int off = 32; off; off >>= 1) cand = min(cand, __shfl_xor(cand, off, 64));
    if (lane == 0) {
        if (cand == 0x7fffffff) {                 // bitwise reproduce failed (paranoia)
            int slot = atomicAdd(nflag, 1);
            flagged[slot] = q;
        } else nn_idx[q] = cand;
    }
}

// K4: exact f64 full rescan for flagged queries — identical semantics to the round-1
// all-f64 kernel (which validated with absmax 0.0). One block per flagged query.
__global__ __launch_bounds__(256)
void nn_refine(const float* __restrict__ pts, const float* __restrict__ dpts,
               const int* __restrict__ flagged, const int* __restrict__ nflag,
               int n, int* __restrict__ nn_idx) {
    int nf = *nflag;
    for (int jj = blockIdx.x; jj < nf; jj += gridDim.x) {
        int q = flagged[jj];
        double m2x = -2.0 * (double)dpts[q * 3 + 0];
        double m2y = -2.0 * (double)dpts[q * 3 + 1];
        double m2z = -2.0 * (double)dpts[q * 3 + 2];
        double best = 1e308; int bi = 0x7fffffff;
        for (int i = threadIdx.x; i < n; i += 256) {
            double x = pts[i * 3 + 0], y = pts[i * 3 + 1], z = pts[i * 3 + 2];
            double ps = x * x + y * y + z * z;
            double v = fma(x, m2x, fma(y, m2y, fma(z, m2z, ps)));
            if (v < best || (v == best && i < bi)) { best = v; bi = i; }
        }
#pragma unroll
        for (int off = 32; off; off >>= 1) {
            double ov = __shfl_down(best, off, 64);
            int oi = __shfl_down(bi, off, 64);
            if (ov < best || (ov == best && oi < bi)) { best = ov; bi = oi; }
        }
        __shared__ double sv[4]; __shared__ int si[4];
        int wid = threadIdx.x >> 6, lane = threadIdx.x & 63;
        if (lane == 0) { sv[wid] = best; si[wid] = bi; }
        __syncthreads();
        if (threadIdx.x == 0) {
            for (int w = 1; w < 4; w++)
                if (sv[w] < best || (sv[w] == best && si[w] < bi)) { best = sv[w]; bi = si[w]; }
            nn_idx[q] = bi;
        }
        __syncthreads();
    }
}

// K5: per-256-element-chunk histogram of sptids (integer LDS atomics -> deterministic)
__global__ __launch_bounds__(256)
void chunk_hist(const int* __restrict__ sptids, int* __restrict__ chunkhist, int m) {
    __shared__ int h[NSEG];
    int ch = blockIdx.x, t = threadIdx.x;
    h[t] = 0; h[t + 256] = 0;
    __syncthreads();
    int i = ch * 256 + t;
    if (i < m) atomicAdd(&h[sptids[i]], 1);
    __syncthreads();
    chunkhist[ch * NSEG + t] = h[t];
    chunkhist[ch * NSEG + t + 256] = h[t + 256];
}

// K6: one block, 512 threads. totals -> exclusive scan over segments -> per-chunk offsets
__global__ __launch_bounds__(NSEG)
void seg_offsets(const int* __restrict__ chunkhist, int* __restrict__ chunkoff, int nch) {
    __shared__ int tot[NSEG];
    int s = threadIdx.x;
    int sum = 0;
    for (int c = 0; c < nch; c++) sum += chunkhist[c * NSEG + s];
    tot[s] = sum;
    __syncthreads();
    int incl = sum;
    for (int off = 1; off < NSEG; off <<= 1) {
        int add = (s >= off) ? tot[s - off] : 0;
        __syncthreads();
        incl += add;
        tot[s] = incl;
        __syncthreads();
    }
    int running = incl - sum;  // exclusive base for this segment
    for (int c = 0; c < nch; c++) {
        chunkoff[c * NSEG + s] = running;
        running += chunkhist[c * NSEG + s];
    }
}

// K7: per-segment f64 sum of gathered scores + argmax -> seg_label.
__global__ __launch_bounds__(256)
void seg_argmax(const int* __restrict__ sptids, const int* __restrict__ nn_idx,
                const float* __restrict__ scores, int* __restrict__ seg_label, int m) {
    int seg = blockIdx.x, t = threadIdx.x;
    double acc[C];
#pragma unroll
    for (int c = 0; c < C; c++) acc[c] = 0.0;
    for (int i = t; i < m; i += 256) {
        if (sptids[i] == seg) {
            const float* sp = scores + (size_t)nn_idx[i] * C;
#pragma unroll
            for (int c = 0; c < C; c++) acc[c] += (double)sp[c];
        }
    }
#pragma unroll
    for (int c = 0; c < C; c++) {
        for (int off = 32; off > 0; off >>= 1) acc[c] += __shfl_down(acc[c], off, 64);
    }
    __shared__ double wsum[4][C];
    int wid = t >> 6, lane = t & 63;
    if (lane == 0) {
#pragma unroll
        for (int c = 0; c < C; c++) wsum[wid][c] = acc[c];
    }
    __syncthreads();
    if (t == 0) {
        int best = 0;
        double bv = wsum[0][0] + wsum[1][0] + wsum[2][0] + wsum[3][0];
        for (int c = 1; c < C; c++) {
            double v = wsum[0][c] + wsum[1][c] + wsum[2][c] + wsum[3][c];
            if (v > bv) { bv = v; best = c; }  // strict > : first max wins
        }
        seg_label[seg] = best;
    }
}

// K8: stable scatter (counting sort) of d_points + labels in original order.
__global__ __launch_bounds__(256)
void scatter_out(const float* __restrict__ dpts, const int* __restrict__ sptids,
                 const int* __restrict__ chunkoff, const int* __restrict__ seg_label,
                 float* __restrict__ out, int m) {
    __shared__ int segs[256];
    int ch = blockIdx.x, t = threadIdx.x;
    int i = ch * 256 + t;
    int seg = (i < m) ? sptids[i] : -1;
    segs[t] = seg;
    __syncthreads();
    if (i >= m) return;
    int rank = 0;
    for (int j = 0; j < t; j++) rank += (segs[j] == seg) ? 1 : 0;  // stable within chunk
    int pos = chunkoff[ch * NSEG + seg] + rank;
    out[(size_t)pos * 3 + 0] = dpts[(size_t)i * 3 + 0];
    out[(size_t)pos * 3 + 1] = dpts[(size_t)i * 3 + 1];
    out[(size_t)pos * 3 + 2] = dpts[(size_t)i * 3 + 2];
    out[(size_t)m * 3 + i] = (float)seg_label[seg];
}

extern "C" void kernel_launch(void* const* d_in, const int* in_sizes, int n_in,
                              void* d_out, int out_size, void* d_ws, size_t ws_size,
                              hipStream_t stream) {
    const float* points = (const float*)d_in[0];
    const float* scores = (const float*)d_in[1];
    const float* dpts   = (const float*)d_in[2];
    const int*   sptids = (const int*)d_in[3];

    int n = in_sizes[0] / 3;
    int m = in_sizes[2] / 3;
    int PC  = (n + PPB - 1) / PPB;     // 32 point chunks
    int QC  = (m + QPB - 1) / QPB;     // 8 query chunks
    int NCH = (m + 255) / 256;         // 64 chunks for counting sort

    char* ws = (char*)d_ws;
    float2* pb       = (float2*)ws;  ws += (size_t)PC * m * sizeof(float2);
    int*    wchunk   = (int*)ws;     ws += (size_t)m * sizeof(int);
    float*  gmin     = (float*)ws;   ws += (size_t)m * sizeof(float);
    int*    nn_idx   = (int*)ws;     ws += (size_t)m * sizeof(int);
    int*    flagged  = (int*)ws;     ws += (size_t)m * sizeof(int);
    int*    nflag    = (int*)ws;     ws += 64;   // keep alignment
    int*    chunkhist= (int*)ws;     ws += (size_t)NCH * NSEG * sizeof(int);
    int*    chunkoff = (int*)ws;     ws += (size_t)NCH * NSEG * sizeof(int);
    int*    seg_label= (int*)ws;     ws += (size_t)NSEG * sizeof(int);

    hipMemsetAsync(nflag, 0, sizeof(int), stream);

    nn_partial<<<dim3(QC, PC), K1_THREADS, 0, stream>>>(points, dpts, n, m, pb);
    nn_reduce<<<(m + 255) / 256, 256, 0, stream>>>(pb, m, PC, wchunk, gmin, flagged, nflag);
    nn_recover<<<(m + 3) / 4, 256, 0, stream>>>(points, dpts, wchunk, gmin, m, nn_idx, flagged, nflag);
    nn_refine<<<256, 256, 0, stream>>>(points, dpts, flagged, nflag, n, nn_idx);
    chunk_hist<<<NCH, 256, 0, stream>>>(sptids, chunkhist, m);
    seg_offsets<<<1, NSEG, 0, stream>>>(chunkhist, chunkoff, NCH);
    seg_argmax<<<NSEG, 256, 0, stream>>>(sptids, nn_idx, scores, seg_label, m);
    scatter_out<<<NCH, 256, 0, stream>>>(dpts, sptids, chunkoff, seg_label, (float*)d_out, m);
}

// Round 3
// 201.819 us; speedup vs baseline: 1.2175x; 1.2175x over previous
//
#include <hip/hip_runtime.h>
#include <cfloat>
#include <cstdint>

#define NSEG 512
#define C 21

// ---- NN config ----
#define K1_THREADS 512
#define QT 4                      // queries per thread
#define QPB (K1_THREADS * QT)     // 2048 queries per block
#define PPB 1024                  // points per block tile
#define EPS_FLAG 2e-4f            // >= 6x worst-case f32 rounding error (delta ~ 3e-5)
#define RF_BLOCKS 2048            // refine: one wave per block

// K0: precompute float4(x, y, z, |p|^2_f32). Single source of truth for the f32
// distance formula -> bitwise-identical v across partial / recover / refine-filter.
__global__ __launch_bounds__(256)
void prep_pts4(const float* __restrict__ pts, float4* __restrict__ pts4, int n) {
    int i = blockIdx.x * 256 + threadIdx.x;
    if (i < n) {
        float x = pts[i * 3 + 0], y = pts[i * 3 + 1], z = pts[i * 3 + 2];
        pts4[i] = make_float4(x, y, z, fmaf(x, x, fmaf(y, y, z * z)));
    }
}

// K1: f32 index-free partial min per (query-chunk, point-chunk).
// v = |p|^2 - 2 q.p  (|q|^2 constant per query -> argmin-invariant).
// Inner loop: 3 fma + 1 fmin = 8 issue-cy/pair/wave.
__global__ __launch_bounds__(K1_THREADS)
void nn_partial(const float4* __restrict__ pts4, const float* __restrict__ dpts,
                int n, int m, float* __restrict__ pbv) {
    __shared__ float4 lp[PPB];
    const int qc = blockIdx.x, pc = blockIdx.y;
    const int t = threadIdx.x;
    const int pbase = pc * PPB;

    for (int j = t; j < PPB; j += K1_THREADS) {
        int p = pbase + j;
        lp[j] = (p < n) ? pts4[p] : make_float4(0.f, 0.f, 0.f, FLT_MAX);
    }
    __syncthreads();

    float m2x[QT], m2y[QT], m2z[QT], b1[QT];
    int qv[QT];
#pragma unroll
    for (int k = 0; k < QT; k++) {
        int qi = qc * QPB + t + k * K1_THREADS;
        qv[k] = qi;
        float qx = 0.f, qy = 0.f, qz = 0.f;
        if (qi < m) {
            qx = dpts[qi * 3 + 0]; qy = dpts[qi * 3 + 1]; qz = dpts[qi * 3 + 2];
        }
        m2x[k] = -2.f * qx; m2y[k] = -2.f * qy; m2z[k] = -2.f * qz;  // exact in f32
        b1[k] = FLT_MAX;
    }

#pragma unroll 4
    for (int j = 0; j < PPB; j++) {
        float4 p = lp[j];
#pragma unroll
        for (int k = 0; k < QT; k++) {
            float v = fmaf(p.x, m2x[k], fmaf(p.y, m2y[k], fmaf(p.z, m2z[k], p.w)));
            b1[k] = fminf(b1[k], v);
        }
    }

#pragma unroll
    for (int k = 0; k < QT; k++)
        if (qv[k] < m) pbv[(size_t)pc * m + qv[k]] = b1[k];
}

// K2: merge chunk mins -> g1 (global f32 min), winner chunk, 2nd-smallest chunk min.
// Cross-chunk ambiguity (g2c - g1 <= EPS, incl. exact ties) -> flag for exact f64 path.
__global__ __launch_bounds__(256)
void nn_reduce(const float* __restrict__ pbv, int m, int PC,
               int* __restrict__ wchunk, float* __restrict__ gmin,
               int* __restrict__ flagged, int* __restrict__ nflag) {
    int q = blockIdx.x * 256 + threadIdx.x;
    if (q >= m) return;
    float g1 = FLT_MAX, g2c = FLT_MAX; int wc = 0;
    for (int pc = 0; pc < PC; pc++) {
        float b = pbv[(size_t)pc * m + q];
        float hi = fmaxf(b, g1);          // loser of (b, g1)
        if (b < g1) wc = pc;              // strict <: first chunk wins
        g1 = fminf(g1, b);
        g2c = fminf(g2c, hi);
    }
    gmin[q] = g1;
    if (g2c - g1 <= EPS_FLAG) {
        int slot = atomicAdd(nflag, 1);
        flagged[slot] = q;
        wchunk[q] = -1;
    } else {
        wchunk[q] = wc;
    }
}

// K3: index recovery, one wave per unflagged query. Rescan the 1024-point winner chunk
// with the bitwise-identical f32 formula; count candidates with v <= g1+EPS.
// count==1 -> that candidate is the exact f64 argmin (error bound: any competitor
// within 2*delta of the min has v32 <= g1+EPS, so count==1 proves isolation).
__global__ __launch_bounds__(256)
void nn_recover(const float4* __restrict__ pts4, const float* __restrict__ dpts,
                const int* __restrict__ wchunk, const float* __restrict__ gmin,
                int n, int m, int* __restrict__ nn_idx,
                int* __restrict__ flagged, int* __restrict__ nflag) {
    int q = blockIdx.x * 4 + (threadIdx.x >> 6);
    int lane = threadIdx.x & 63;
    if (q >= m) return;
    int wc = wchunk[q];
    if (wc < 0) return;
    float thr = gmin[q] + EPS_FLAG;
    float m2x = -2.f * dpts[q * 3 + 0];
    float m2y = -2.f * dpts[q * 3 + 1];
    float m2z = -2.f * dpts[q * 3 + 2];
    int pbase = wc * PPB;
    int cand = 0x7fffffff, cnt = 0;
#pragma unroll 4
    for (int it = 0; it < PPB / 64; it++) {
        int j = pbase + lane + it * 64;
        float4 p = (j < n) ? pts4[j] : make_float4(0.f, 0.f, 0.f, FLT_MAX);
        float v = fmaf(p.x, m2x, fmaf(p.y, m2y, fmaf(p.z, m2z, p.w)));
        if (v <= thr) { cnt++; cand = min(cand, j); }
    }
#pragma unroll
    for (int off = 32; off; off >>= 1) {
        cand = min(cand, __shfl_xor(cand, off, 64));
        cnt += __shfl_xor(cnt, off, 64);
    }
    if (lane == 0) {
        if (cnt == 1) nn_idx[q] = cand;
        else {                                  // within-chunk near-tie (or paranoia)
            int slot = atomicAdd(nflag, 1);
            flagged[slot] = q;
        }
    }
}

// K4: exact f64 resolution for flagged queries. One WAVE per query, grid-stride.
// f32 filter (6 ops) skips the f64 eval for ~all points; f64 exact on candidates.
// Semantics identical to a full f64 argmin with lowest-index tie-break.
__global__ __launch_bounds__(64)
void nn_refine(const float4* __restrict__ pts4, const float* __restrict__ dpts,
               const int* __restrict__ flagged, const int* __restrict__ nflag,
               const float* __restrict__ gmin, int n, int* __restrict__ nn_idx) {
    int nf = *nflag;
    int lane = threadIdx.x;
    for (int jj = blockIdx.x; jj < nf; jj += gridDim.x) {
        int q = flagged[jj];
        float fx = dpts[q * 3 + 0], fy = dpts[q * 3 + 1], fz = dpts[q * 3 + 2];
        float fm2x = -2.f * fx, fm2y = -2.f * fy, fm2z = -2.f * fz;
        float thr = gmin[q] + EPS_FLAG;
        double m2x = -2.0 * (double)fx, m2y = -2.0 * (double)fy, m2z = -2.0 * (double)fz;
        double best = 1e308; int bi = 0x7fffffff;
        for (int i = lane; i < n; i += 64) {
            float4 p = pts4[i];
            float v = fmaf(p.x, fm2x, fmaf(p.y, fm2y, fmaf(p.z, fm2z, p.w)));
            if (v <= thr) {
                double x = (double)p.x, y = (double)p.y, z = (double)p.z;
                double ps = x * x + y * y + z * z;
                double dv = fma(x, m2x, fma(y, m2y, fma(z, m2z, ps)));
                if (dv < best || (dv == best && i < bi)) { best = dv; bi = i; }
            }
        }
#pragma unroll
        for (int off = 32; off; off >>= 1) {
            double ov = __shfl_down(best, off, 64);
            int oi = __shfl_down(bi, off, 64);
            if (ov < best || (ov == best && oi < bi)) { best = ov; bi = oi; }
        }
        if (lane == 0) nn_idx[q] = bi;
    }
}

// K5: per-256-element-chunk histogram of sptids (integer LDS atomics -> deterministic)
__global__ __launch_bounds__(256)
void chunk_hist(const int* __restrict__ sptids, int* __restrict__ chunkhist, int m) {
    __shared__ int h[NSEG];
    int ch = blockIdx.x, t = threadIdx.x;
    h[t] = 0; h[t + 256] = 0;
    __syncthreads();
    int i = ch * 256 + t;
    if (i < m) atomicAdd(&h[sptids[i]], 1);
    __syncthreads();
    chunkhist[ch * NSEG + t] = h[t];
    chunkhist[ch * NSEG + t + 256] = h[t + 256];
}

// K6: one block, 512 threads. totals -> exclusive scan over segments -> per-chunk offsets
__global__ __launch_bounds__(NSEG)
void seg_offsets(const int* __restrict__ chunkhist, int* __restrict__ chunkoff, int nch) {
    __shared__ int tot[NSEG];
    int s = threadIdx.x;
    int sum = 0;
    for (int c = 0; c < nch; c++) sum += chunkhist[c * NSEG + s];
    tot[s] = sum;
    __syncthreads();
    int incl = sum;
    for (int off = 1; off < NSEG; off <<= 1) {
        int add = (s >= off) ? tot[s - off] : 0;
        __syncthreads();
        incl += add;
        tot[s] = incl;
        __syncthreads();
    }
    int running = incl - sum;  // exclusive base for this segment
    for (int c = 0; c < nch; c++) {
        chunkoff[c * NSEG + s] = running;
        running += chunkhist[c * NSEG + s];
    }
}

// K7: per-segment f64 sum of gathered scores + argmax -> seg_label.
// argmax(sum) == argmax(mean) since count is a positive per-segment scalar.
__global__ __launch_bounds__(256)
void seg_argmax(const int* __restrict__ sptids, const int* __restrict__ nn_idx,
                const float* __restrict__ scores, int* __restrict__ seg_label, int m) {
    int seg = blockIdx.x, t = threadIdx.x;
    double acc[C];
#pragma unroll
    for (int c = 0; c < C; c++) acc[c] = 0.0;
    for (int i = t; i < m; i += 256) {
        if (sptids[i] == seg) {
            const float* sp = scores + (size_t)nn_idx[i] * C;
#pragma unroll
            for (int c = 0; c < C; c++) acc[c] += (double)sp[c];
        }
    }
#pragma unroll
    for (int c = 0; c < C; c++) {
        for (int off = 32; off > 0; off >>= 1) acc[c] += __shfl_down(acc[c], off, 64);
    }
    __shared__ double wsum[4][C];
    int wid = t >> 6, lane = t & 63;
    if (lane == 0) {
#pragma unroll
        for (int c = 0; c < C; c++) wsum[wid][c] = acc[c];
    }
    __syncthreads();
    if (t == 0) {
        int best = 0;
        double bv = wsum[0][0] + wsum[1][0] + wsum[2][0] + wsum[3][0];
        for (int c = 1; c < C; c++) {
            double v = wsum[0][c] + wsum[1][c] + wsum[2][c] + wsum[3][c];
            if (v > bv) { bv = v; best = c; }  // strict > : first max wins
        }
        seg_label[seg] = best;
    }
}

// K8: stable scatter (counting sort) of d_points + labels in original order.
__global__ __launch_bounds__(256)
void scatter_out(const float* __restrict__ dpts, const int* __restrict__ sptids,
                 const int* __restrict__ chunkoff, const int* __restrict__ seg_label,
                 float* __restrict__ out, int m) {
    __shared__ int segs[256];
    int ch = blockIdx.x, t = threadIdx.x;
    int i = ch * 256 + t;
    int seg = (i < m) ? sptids[i] : -1;
    segs[t] = seg;
    __syncthreads();
    if (i >= m) return;
    int rank = 0;
    for (int j = 0; j < t; j++) rank += (segs[j] == seg) ? 1 : 0;  // stable within chunk
    int pos = chunkoff[ch * NSEG + seg] + rank;
    out[(size_t)pos * 3 + 0] = dpts[(size_t)i * 3 + 0];
    out[(size_t)pos * 3 + 1] = dpts[(size_t)i * 3 + 1];
    out[(size_t)pos * 3 + 2] = dpts[(size_t)i * 3 + 2];
    out[(size_t)m * 3 + i] = (float)seg_label[seg];
}

extern "C" void kernel_launch(void* const* d_in, const int* in_sizes, int n_in,
                              void* d_out, int out_size, void* d_ws, size_t ws_size,
                              hipStream_t stream) {
    const float* points = (const float*)d_in[0];
    const float* scores = (const float*)d_in[1];
    const float* dpts   = (const float*)d_in[2];
    const int*   sptids = (const int*)d_in[3];

    int n = in_sizes[0] / 3;
    int m = in_sizes[2] / 3;
    int PC  = (n + PPB - 1) / PPB;     // 32 point chunks
    int QC  = (m + QPB - 1) / QPB;     // 8 query chunks
    int NCH = (m + 255) / 256;         // 64 chunks for counting sort

    char* ws = (char*)d_ws;
    float4* pts4     = (float4*)ws;  ws += (size_t)n * sizeof(float4);
    float*  pbv      = (float*)ws;   ws += (size_t)PC * m * sizeof(float);
    int*    wchunk   = (int*)ws;     ws += (size_t)m * sizeof(int);
    float*  gmin     = (float*)ws;   ws += (size_t)m * sizeof(float);
    int*    nn_idx   = (int*)ws;     ws += (size_t)m * sizeof(int);
    int*    flagged  = (int*)ws;     ws += (size_t)m * sizeof(int);
    int*    nflag    = (int*)ws;     ws += 64;   // keep alignment
    int*    chunkhist= (int*)ws;     ws += (size_t)NCH * NSEG * sizeof(int);
    int*    chunkoff = (int*)ws;     ws += (size_t)NCH * NSEG * sizeof(int);
    int*    seg_label= (int*)ws;     ws += (size_t)NSEG * sizeof(int);

    hipMemsetAsync(nflag, 0, sizeof(int), stream);

    prep_pts4<<<(n + 255) / 256, 256, 0, stream>>>(points, pts4, n);
    nn_partial<<<dim3(QC, PC), K1_THREADS, 0, stream>>>(pts4, dpts, n, m, pbv);
    nn_reduce<<<(m + 255) / 256, 256, 0, stream>>>(pbv, m, PC, wchunk, gmin, flagged, nflag);
    nn_recover<<<(m + 3) / 4, 256, 0, stream>>>(pts4, dpts, wchunk, gmin, n, m, nn_idx, flagged, nflag);
    nn_refine<<<RF_BLOCKS, 64, 0, stream>>>(pts4, dpts, flagged, nflag, gmin, n, nn_idx);
    chunk_hist<<<NCH, 256, 0, stream>>>(sptids, chunkhist, m);
    seg_offsets<<<1, NSEG, 0, stream>>>(chunkhist, chunkoff, NCH);
    seg_argmax<<<NSEG, 256, 0, stream>>>(sptids, nn_idx, scores, seg_label, m);
    scatter_out<<<NCH, 256, 0, stream>>>(dpts, sptids, chunkoff, seg_label, (float*)d_out, m);
}

// Round 4
// 143.331 us; speedup vs baseline: 1.7143x; 1.4081x over previous
//
#include <hip/hip_runtime.h>
#include <cfloat>
#include <cstdint>

#define NSEG 512
#define C 21

// ---- NN config ----
#define K1_THREADS 512
#define QT 4                      // queries per thread
#define QPB (K1_THREADS * QT)     // 2048 queries per block
#define PPB 1024                  // points per block tile
#define EPS_FLAG 2e-4f            // >= 4x worst-case f32 chain error (2*delta ~ 5e-5)
#define RF_BLOCKS 2048

// K0: precompute float4(x, y, z, |p|^2_f32). Single source of truth for the f32
// distance formula -> bitwise-identical v across partial / recover / refine-filter.
__global__ __launch_bounds__(256)
void prep_pts4(const float* __restrict__ pts, float4* __restrict__ pts4, int n) {
    int i = blockIdx.x * 256 + threadIdx.x;
    if (i < n) {
        float x = pts[i * 3 + 0], y = pts[i * 3 + 1], z = pts[i * 3 + 2];
        pts4[i] = make_float4(x, y, z, fmaf(x, x, fmaf(y, y, z * z)));
    }
}

// K1: f32 index-free partial min per (query-chunk, point-chunk).
// v = |p|^2 - 2 q.p  (|q|^2 constant per query -> argmin-invariant).
__global__ __launch_bounds__(K1_THREADS)
void nn_partial(const float4* __restrict__ pts4, const float* __restrict__ dpts,
                int n, int m, float* __restrict__ pbv) {
    __shared__ float4 lp[PPB];
    const int qc = blockIdx.x, pc = blockIdx.y;
    const int t = threadIdx.x;
    const int pbase = pc * PPB;

    for (int j = t; j < PPB; j += K1_THREADS) {
        int p = pbase + j;
        lp[j] = (p < n) ? pts4[p] : make_float4(0.f, 0.f, 0.f, FLT_MAX);
    }
    __syncthreads();

    float m2x[QT], m2y[QT], m2z[QT], b1[QT];
    int qv[QT];
#pragma unroll
    for (int k = 0; k < QT; k++) {
        int qi = qc * QPB + t + k * K1_THREADS;
        qv[k] = qi;
        float qx = 0.f, qy = 0.f, qz = 0.f;
        if (qi < m) {
            qx = dpts[qi * 3 + 0]; qy = dpts[qi * 3 + 1]; qz = dpts[qi * 3 + 2];
        }
        m2x[k] = -2.f * qx; m2y[k] = -2.f * qy; m2z[k] = -2.f * qz;  // exact in f32
        b1[k] = FLT_MAX;
    }

#pragma unroll 4
    for (int j = 0; j < PPB; j++) {
        float4 p = lp[j];
#pragma unroll
        for (int k = 0; k < QT; k++) {
            float v = fmaf(p.x, m2x[k], fmaf(p.y, m2y[k], fmaf(p.z, m2z[k], p.w)));
            b1[k] = fminf(b1[k], v);
        }
    }

#pragma unroll
    for (int k = 0; k < QT; k++)
        if (qv[k] < m) pbv[(size_t)pc * m + qv[k]] = b1[k];
}

// K2: merge chunk mins -> g1 (global f32 min), winner chunk, 2nd-smallest chunk min.
// Cross-chunk ambiguity (g2c - g1 <= EPS, incl. exact ties) -> flag for exact f64 path.
__global__ __launch_bounds__(256)
void nn_reduce(const float* __restrict__ pbv, int m, int PC,
               int* __restrict__ wchunk, float* __restrict__ gmin,
               int* __restrict__ flagged, int* __restrict__ nflag) {
    int q = blockIdx.x * 256 + threadIdx.x;
    if (q >= m) return;
    float g1 = FLT_MAX, g2c = FLT_MAX; int wc = 0;
    for (int pc = 0; pc < PC; pc++) {
        float b = pbv[(size_t)pc * m + q];
        float hi = fmaxf(b, g1);          // loser of (b, g1)
        if (b < g1) wc = pc;              // strict <: first chunk wins
        g1 = fminf(g1, b);
        g2c = fminf(g2c, hi);
    }
    gmin[q] = g1;
    if (g2c - g1 <= EPS_FLAG) {
        int slot = atomicAdd(nflag, 1);
        flagged[slot] = q;
        wchunk[q] = -1;
    } else {
        wchunk[q] = wc;
    }
}

// K3: index recovery, one wave per unflagged query. Rescan the 1024-point winner chunk
// with the bitwise-identical f32 formula; count candidates with v <= g1+EPS.
// count==1 -> that candidate is the exact f64 argmin; else flag.
__global__ __launch_bounds__(256)
void nn_recover(const float4* __restrict__ pts4, const float* __restrict__ dpts,
                const int* __restrict__ wchunk, const float* __restrict__ gmin,
                int n, int m, int* __restrict__ nn_idx,
                int* __restrict__ flagged, int* __restrict__ nflag) {
    int q = blockIdx.x * 4 + (threadIdx.x >> 6);
    int lane = threadIdx.x & 63;
    if (q >= m) return;
    int wc = wchunk[q];
    if (wc < 0) return;
    float thr = gmin[q] + EPS_FLAG;
    float m2x = -2.f * dpts[q * 3 + 0];
    float m2y = -2.f * dpts[q * 3 + 1];
    float m2z = -2.f * dpts[q * 3 + 2];
    int pbase = wc * PPB;
    int cand = 0x7fffffff, cnt = 0;
#pragma unroll 4
    for (int it = 0; it < PPB / 64; it++) {
        int j = pbase + lane + it * 64;
        float4 p = (j < n) ? pts4[j] : make_float4(0.f, 0.f, 0.f, FLT_MAX);
        float v = fmaf(p.x, m2x, fmaf(p.y, m2y, fmaf(p.z, m2z, p.w)));
        if (v <= thr) { cnt++; cand = min(cand, j); }
    }
#pragma unroll
    for (int off = 32; off; off >>= 1) {
        cand = min(cand, __shfl_xor(cand, off, 64));
        cnt += __shfl_xor(cnt, off, 64);
    }
    if (lane == 0) {
        if (cnt == 1) nn_idx[q] = cand;
        else {                                  // within-chunk near-tie (or paranoia)
            int slot = atomicAdd(nflag, 1);
            flagged[slot] = q;
        }
    }
}

// K4: exact f64 resolution for flagged queries. One 256-THREAD BLOCK per query,
// grid-stride. Per thread: 128 points, unrolled x4 with batched loads (breaks the
// dependent-load chain: 32 batches instead of 512 serial iterations).
// f32 filter (v <= gmin+EPS) guards the f64 exact eval; bound 2*delta ~ 5e-5 << EPS.
// Semantics identical to full f64 argmin with lowest-index tie-break.
__global__ __launch_bounds__(256)
void nn_refine(const float4* __restrict__ pts4, const float* __restrict__ dpts,
               const int* __restrict__ flagged, const int* __restrict__ nflag,
               const float* __restrict__ gmin, int n, int* __restrict__ nn_idx) {
    int nf = *nflag;
    int t = threadIdx.x;
    int wid = t >> 6, lane = t & 63;
    __shared__ double sv[4];
    __shared__ int si[4];

    for (int jj = blockIdx.x; jj < nf; jj += gridDim.x) {
        int q = flagged[jj];
        float fx = dpts[q * 3 + 0], fy = dpts[q * 3 + 1], fz = dpts[q * 3 + 2];
        float fm2x = -2.f * fx, fm2y = -2.f * fy, fm2z = -2.f * fz;
        float thr = gmin[q] + EPS_FLAG;
        double m2x = -2.0 * (double)fx, m2y = -2.0 * (double)fy, m2z = -2.0 * (double)fz;
        double best = 1e308; int bi = 0x7fffffff;

        auto eval64 = [&](int i, float4 p) {
            double x = (double)p.x, y = (double)p.y, z = (double)p.z;
            double ps = x * x + y * y + z * z;
            double dv = fma(x, m2x, fma(y, m2y, fma(z, m2z, ps)));
            if (dv < best || (dv == best && i < bi)) { best = dv; bi = i; }
        };

        int base = 0;
        for (; base + 1024 <= n; base += 1024) {
            int i0 = base + t;
            float4 p0 = pts4[i0];
            float4 p1 = pts4[i0 + 256];
            float4 p2 = pts4[i0 + 512];
            float4 p3 = pts4[i0 + 768];
            float v0 = fmaf(p0.x, fm2x, fmaf(p0.y, fm2y, fmaf(p0.z, fm2z, p0.w)));
            float v1 = fmaf(p1.x, fm2x, fmaf(p1.y, fm2y, fmaf(p1.z, fm2z, p1.w)));
            float v2 = fmaf(p2.x, fm2x, fmaf(p2.y, fm2y, fmaf(p2.z, fm2z, p2.w)));
            float v3 = fmaf(p3.x, fm2x, fmaf(p3.y, fm2y, fmaf(p3.z, fm2z, p3.w)));
            if (v0 <= thr) eval64(i0, p0);
            if (v1 <= thr) eval64(i0 + 256, p1);
            if (v2 <= thr) eval64(i0 + 512, p2);
            if (v3 <= thr) eval64(i0 + 768, p3);
        }
        for (int i = base + t; i < n; i += 256) {   // tail (n % 1024 != 0)
            float4 p = pts4[i];
            float v = fmaf(p.x, fm2x, fmaf(p.y, fm2y, fmaf(p.z, fm2z, p.w)));
            if (v <= thr) eval64(i, p);
        }

#pragma unroll
        for (int off = 32; off; off >>= 1) {
            double ov = __shfl_down(best, off, 64);
            int oi = __shfl_down(bi, off, 64);
            if (ov < best || (ov == best && oi < bi)) { best = ov; bi = oi; }
        }
        if (lane == 0) { sv[wid] = best; si[wid] = bi; }
        __syncthreads();
        if (t == 0) {
            for (int w = 1; w < 4; w++)
                if (sv[w] < best || (sv[w] == best && si[w] < bi)) { best = sv[w]; bi = si[w]; }
            nn_idx[q] = bi;
        }
        __syncthreads();   // protect LDS before next grid-stride iteration
    }
}

// K5: per-256-element-chunk histogram of sptids (integer LDS atomics -> deterministic)
__global__ __launch_bounds__(256)
void chunk_hist(const int* __restrict__ sptids, int* __restrict__ chunkhist, int m) {
    __shared__ int h[NSEG];
    int ch = blockIdx.x, t = threadIdx.x;
    h[t] = 0; h[t + 256] = 0;
    __syncthreads();
    int i = ch * 256 + t;
    if (i < m) atomicAdd(&h[sptids[i]], 1);
    __syncthreads();
    chunkhist[ch * NSEG + t] = h[t];
    chunkhist[ch * NSEG + t + 256] = h[t + 256];
}

// K6: one block, 512 threads. totals -> exclusive scan over segments -> per-chunk offsets
__global__ __launch_bounds__(NSEG)
void seg_offsets(const int* __restrict__ chunkhist, int* __restrict__ chunkoff, int nch) {
    __shared__ int tot[NSEG];
    int s = threadIdx.x;
    int sum = 0;
    for (int c = 0; c < nch; c++) sum += chunkhist[c * NSEG + s];
    tot[s] = sum;
    __syncthreads();
    int incl = sum;
    for (int off = 1; off < NSEG; off <<= 1) {
        int add = (s >= off) ? tot[s - off] : 0;
        __syncthreads();
        incl += add;
        tot[s] = incl;
        __syncthreads();
    }
    int running = incl - sum;  // exclusive base for this segment
    for (int c = 0; c < nch; c++) {
        chunkoff[c * NSEG + s] = running;
        running += chunkhist[c * NSEG + s];
    }
}

// K7: per-segment f64 sum of gathered scores + argmax -> seg_label.
// argmax(sum) == argmax(mean) since count is a positive per-segment scalar.
__global__ __launch_bounds__(256)
void seg_argmax(const int* __restrict__ sptids, const int* __restrict__ nn_idx,
                const float* __restrict__ scores, int* __restrict__ seg_label, int m) {
    int seg = blockIdx.x, t = threadIdx.x;
    double acc[C];
#pragma unroll
    for (int c = 0; c < C; c++) acc[c] = 0.0;
    for (int i = t; i < m; i += 256) {
        if (sptids[i] == seg) {
            const float* sp = scores + (size_t)nn_idx[i] * C;
#pragma unroll
            for (int c = 0; c < C; c++) acc[c] += (double)sp[c];
        }
    }
#pragma unroll
    for (int c = 0; c < C; c++) {
        for (int off = 32; off > 0; off >>= 1) acc[c] += __shfl_down(acc[c], off, 64);
    }
    __shared__ double wsum[4][C];
    int wid = t >> 6, lane = t & 63;
    if (lane == 0) {
#pragma unroll
        for (int c = 0; c < C; c++) wsum[wid][c] = acc[c];
    }
    __syncthreads();
    if (t == 0) {
        int best = 0;
        double bv = wsum[0][0] + wsum[1][0] + wsum[2][0] + wsum[3][0];
        for (int c = 1; c < C; c++) {
            double v = wsum[0][c] + wsum[1][c] + wsum[2][c] + wsum[3][c];
            if (v > bv) { bv = v; best = c; }  // strict > : first max wins
        }
        seg_label[seg] = best;
    }
}

// K8: stable scatter (counting sort) of d_points + labels in original order.
__global__ __launch_bounds__(256)
void scatter_out(const float* __restrict__ dpts, const int* __restrict__ sptids,
                 const int* __restrict__ chunkoff, const int* __restrict__ seg_label,
                 float* __restrict__ out, int m) {
    __shared__ int segs[256];
    int ch = blockIdx.x, t = threadIdx.x;
    int i = ch * 256 + t;
    int seg = (i < m) ? sptids[i] : -1;
    segs[t] = seg;
    __syncthreads();
    if (i >= m) return;
    int rank = 0;
    for (int j = 0; j < t; j++) rank += (segs[j] == seg) ? 1 : 0;  // stable within chunk
    int pos = chunkoff[ch * NSEG + seg] + rank;
    out[(size_t)pos * 3 + 0] = dpts[(size_t)i * 3 + 0];
    out[(size_t)pos * 3 + 1] = dpts[(size_t)i * 3 + 1];
    out[(size_t)pos * 3 + 2] = dpts[(size_t)i * 3 + 2];
    out[(size_t)m * 3 + i] = (float)seg_label[seg];
}

extern "C" void kernel_launch(void* const* d_in, const int* in_sizes, int n_in,
                              void* d_out, int out_size, void* d_ws, size_t ws_size,
                              hipStream_t stream) {
    const float* points = (const float*)d_in[0];
    const float* scores = (const float*)d_in[1];
    const float* dpts   = (const float*)d_in[2];
    const int*   sptids = (const int*)d_in[3];

    int n = in_sizes[0] / 3;
    int m = in_sizes[2] / 3;
    int PC  = (n + PPB - 1) / PPB;     // 32 point chunks
    int QC  = (m + QPB - 1) / QPB;     // 8 query chunks
    int NCH = (m + 255) / 256;         // 64 chunks for counting sort

    char* ws = (char*)d_ws;
    float4* pts4     = (float4*)ws;  ws += (size_t)n * sizeof(float4);
    float*  pbv      = (float*)ws;   ws += (size_t)PC * m * sizeof(float);
    int*    wchunk   = (int*)ws;     ws += (size_t)m * sizeof(int);
    float*  gmin     = (float*)ws;   ws += (size_t)m * sizeof(float);
    int*    nn_idx   = (int*)ws;     ws += (size_t)m * sizeof(int);
    int*    flagged  = (int*)ws;     ws += (size_t)m * sizeof(int);
    int*    nflag    = (int*)ws;     ws += 64;   // keep alignment
    int*    chunkhist= (int*)ws;     ws += (size_t)NCH * NSEG * sizeof(int);
    int*    chunkoff = (int*)ws;     ws += (size_t)NCH * NSEG * sizeof(int);
    int*    seg_label= (int*)ws;     ws += (size_t)NSEG * sizeof(int);

    hipMemsetAsync(nflag, 0, sizeof(int), stream);

    prep_pts4<<<(n + 255) / 256, 256, 0, stream>>>(points, pts4, n);
    nn_partial<<<dim3(QC, PC), K1_THREADS, 0, stream>>>(pts4, dpts, n, m, pbv);
    nn_reduce<<<(m + 255) / 256, 256, 0, stream>>>(pbv, m, PC, wchunk, gmin, flagged, nflag);
    nn_recover<<<(m + 3) / 4, 256, 0, stream>>>(pts4, dpts, wchunk, gmin, n, m, nn_idx, flagged, nflag);
    nn_refine<<<RF_BLOCKS, 256, 0, stream>>>(pts4, dpts, flagged, nflag, gmin, n, nn_idx);
    chunk_hist<<<NCH, 256, 0, stream>>>(sptids, chunkhist, m);
    seg_offsets<<<1, NSEG, 0, stream>>>(chunkhist, chunkoff, NCH);
    seg_argmax<<<NSEG, 256, 0, stream>>>(sptids, nn_idx, scores, seg_label, m);
    scatter_out<<<NCH, 256, 0, stream>>>(dpts, sptids, chunkoff, seg_label, (float*)d_out, m);
}

// Round 5
// 101.954 us; speedup vs baseline: 2.4100x; 1.4058x over previous
//
#include <hip/hip_runtime.h>
#include <cfloat>
#include <cstdint>

#define NSEG 512
#define C 21

// ---- NN config ----
#define K1_THREADS 256
#define QT 8                      // queries per thread
#define QPB (K1_THREADS * QT)     // 2048 queries per block
#define PPB 512                   // points per block tile
#define PCMAX 64                  // = n/PPB = 64 chunks (one per lane in merge)
#define EPS_FLAG 2e-4f            // >= 4x worst-case f32 chain error (2*delta ~ 5e-5)

// K0: precompute float4(x, y, z, |p|^2_f32); zero the flag counter.
// Single source of truth for the f32 distance chain -> bitwise-identical v
// across partial / merge-rescan / refine-filter.
__global__ __launch_bounds__(256)
void prep_pts4(const float* __restrict__ pts, float4* __restrict__ pts4, int n,
               int* __restrict__ nflag) {
    int i = blockIdx.x * 256 + threadIdx.x;
    if (i == 0) *nflag = 0;
    if (i < n) {
        float x = pts[i * 3 + 0], y = pts[i * 3 + 1], z = pts[i * 3 + 2];
        pts4[i] = make_float4(x, y, z, fmaf(x, x, fmaf(y, y, z * z)));
    }
}

// K1: f32 index-free partial min per (query-chunk, point-chunk).
// v = |p|^2 - 2 q.p  (|q|^2 constant per query -> argmin-invariant).
// Point-pairs + min3 fusion: 3.5 VALU ops per pair (7 fma + 1 min3 per 2 points).
__global__ __launch_bounds__(K1_THREADS, 2)
void nn_partial(const float4* __restrict__ pts4, const float* __restrict__ dpts,
                int n, int m, float* __restrict__ pbv) {
    __shared__ float4 lp[PPB];
    const int qc = blockIdx.x, pc = blockIdx.y;
    const int t = threadIdx.x;
    const int pbase = pc * PPB;

    for (int j = t; j < PPB; j += K1_THREADS) {
        int p = pbase + j;
        lp[j] = (p < n) ? pts4[p] : make_float4(0.f, 0.f, 0.f, FLT_MAX);
    }
    __syncthreads();

    float m2x[QT], m2y[QT], m2z[QT], b1[QT];
    int qv[QT];
#pragma unroll
    for (int k = 0; k < QT; k++) {
        int qi = qc * QPB + t + k * K1_THREADS;
        qv[k] = qi;
        float qx = 0.f, qy = 0.f, qz = 0.f;
        if (qi < m) {
            qx = dpts[qi * 3 + 0]; qy = dpts[qi * 3 + 1]; qz = dpts[qi * 3 + 2];
        }
        m2x[k] = -2.f * qx; m2y[k] = -2.f * qy; m2z[k] = -2.f * qz;  // exact in f32
        b1[k] = FLT_MAX;
    }

#pragma unroll 2
    for (int j = 0; j < PPB; j += 2) {
        float4 p0 = lp[j], p1 = lp[j + 1];
#pragma unroll
        for (int k = 0; k < QT; k++) {
            float v0 = fmaf(p0.x, m2x[k], fmaf(p0.y, m2y[k], fmaf(p0.z, m2z[k], p0.w)));
            float v1 = fmaf(p1.x, m2x[k], fmaf(p1.y, m2y[k], fmaf(p1.z, m2z[k], p1.w)));
            b1[k] = fminf(fminf(v0, v1), b1[k]);   // -> v_min3_f32
        }
    }

#pragma unroll
    for (int k = 0; k < QT; k++)
        if (qv[k] < m) pbv[(size_t)pc * m + qv[k]] = b1[k];
}

// K2: fused reduce+recover, one WAVE per query. Lane pc holds chunk pc's min;
// butterfly-reduce (b1, winner-chunk id1 with lowest-id tie, second-best b2).
// Cross-chunk near-tie (b2-b1<=EPS) -> flag. Else rescan winner chunk with the
// bitwise-identical chain; unique candidate (cnt==1) -> exact argmin, else flag.
__global__ __launch_bounds__(256)
void nn_merge(const float4* __restrict__ pts4, const float* __restrict__ dpts,
              const float* __restrict__ pbv, int n, int m, int PC,
              float* __restrict__ gmin, int* __restrict__ nn_idx,
              int* __restrict__ flagged, int* __restrict__ nflag) {
    int q = blockIdx.x * 4 + (threadIdx.x >> 6);
    int lane = threadIdx.x & 63;
    if (q >= m) return;

    float b1 = (lane < PC) ? pbv[(size_t)lane * m + q] : FLT_MAX;
    int id1 = lane;
    float b2 = FLT_MAX;
#pragma unroll
    for (int off = 1; off < 64; off <<= 1) {
        float ob1 = __shfl_xor(b1, off, 64);
        int   oid = __shfl_xor(id1, off, 64);
        float ob2 = __shfl_xor(b2, off, 64);
        float nb2 = fminf(fminf(b2, ob2), fmaxf(b1, ob1));
        if (ob1 < b1 || (ob1 == b1 && oid < id1)) id1 = oid;
        b1 = fminf(b1, ob1);
        b2 = nb2;
    }
    if (lane == 0) gmin[q] = b1;
    float thr = b1 + EPS_FLAG;
    if (b2 <= thr) {
        if (lane == 0) { int s = atomicAdd(nflag, 1); flagged[s] = q; }
        return;
    }
    float m2x = -2.f * dpts[q * 3 + 0];
    float m2y = -2.f * dpts[q * 3 + 1];
    float m2z = -2.f * dpts[q * 3 + 2];
    int pbase = id1 * PPB;
    int cand = 0x7fffffff, cnt = 0;
#pragma unroll
    for (int it = 0; it < PPB / 64; it++) {
        int j = pbase + lane + it * 64;
        float4 p = (j < n) ? pts4[j] : make_float4(0.f, 0.f, 0.f, FLT_MAX);
        float v = fmaf(p.x, m2x, fmaf(p.y, m2y, fmaf(p.z, m2z, p.w)));
        if (v <= thr) { cnt++; cand = min(cand, j); }
    }
#pragma unroll
    for (int off = 32; off; off >>= 1) {
        cand = min(cand, __shfl_xor(cand, off, 64));
        cnt += __shfl_xor(cnt, off, 64);
    }
    if (lane == 0) {
        if (cnt == 1) nn_idx[q] = cand;
        else { int s = atomicAdd(nflag, 1); flagged[s] = q; }
    }
}

// K3: exact f64 resolution for flagged queries, CHUNK-PRUNED: only chunks whose
// f32 min <= g1+EPS can contain an f64-argmin candidate (EPS >= 2*delta), so
// scan just those (typically 1-3 of 64). One 256-thread block per query.
// Exact f64 eval + lowest-index tie-break == full-scan f64 semantics.
__global__ __launch_bounds__(256)
void nn_refine(const float4* __restrict__ pts4, const float* __restrict__ dpts,
               const int* __restrict__ flagged, const int* __restrict__ nflag,
               const float* __restrict__ gmin, const float* __restrict__ pbv,
               int n, int m, int PC, int* __restrict__ nn_idx) {
    int nf = *nflag;
    int t = threadIdx.x;
    int wid = t >> 6, lane = t & 63;
    __shared__ int oklist[PCMAX];
    __shared__ int nok;
    __shared__ double sv[4];
    __shared__ int si[4];

    for (int jj = blockIdx.x; jj < nf; jj += gridDim.x) {
        int q = flagged[jj];
        float g1 = gmin[q];
        float thr = g1 + EPS_FLAG;
        if (t == 0) nok = 0;
        __syncthreads();
        if (t < PC) {
            if (pbv[(size_t)t * m + q] <= thr) {
                int s = atomicAdd(&nok, 1);
                oklist[s] = t;                 // unordered; result is order-invariant
            }
        }
        __syncthreads();

        float fx = dpts[q * 3 + 0], fy = dpts[q * 3 + 1], fz = dpts[q * 3 + 2];
        float fm2x = -2.f * fx, fm2y = -2.f * fy, fm2z = -2.f * fz;
        double m2x = -2.0 * (double)fx, m2y = -2.0 * (double)fy, m2z = -2.0 * (double)fz;
        double best = 1e308; int bi = 0x7fffffff;

        int nk = nok;
        for (int s = 0; s < nk; s++) {
            int pbase = oklist[s] * PPB;
#pragma unroll
            for (int it = 0; it < PPB / 256; it++) {
                int i = pbase + t + it * 256;
                if (i >= n) continue;
                float4 p = pts4[i];
                float v = fmaf(p.x, fm2x, fmaf(p.y, fm2y, fmaf(p.z, fm2z, p.w)));
                if (v <= thr) {
                    double x = (double)p.x, y = (double)p.y, z = (double)p.z;
                    double ps = x * x + y * y + z * z;
                    double dv = fma(x, m2x, fma(y, m2y, fma(z, m2z, ps)));
                    if (dv < best || (dv == best && i < bi)) { best = dv; bi = i; }
                }
            }
        }

#pragma unroll
        for (int off = 32; off; off >>= 1) {
            double ov = __shfl_down(best, off, 64);
            int oi = __shfl_down(bi, off, 64);
            if (ov < best || (ov == best && oi < bi)) { best = ov; bi = oi; }
        }
        if (lane == 0) { sv[wid] = best; si[wid] = bi; }
        __syncthreads();
        if (t == 0) {
            for (int w = 1; w < 4; w++)
                if (sv[w] < best || (sv[w] == best && si[w] < bi)) { best = sv[w]; bi = si[w]; }
            nn_idx[q] = bi;
        }
        __syncthreads();
    }
}

// K4: per-256-element-chunk histogram of sptids (integer LDS atomics -> deterministic)
__global__ __launch_bounds__(256)
void chunk_hist(const int* __restrict__ sptids, int* __restrict__ chunkhist, int m) {
    __shared__ int h[NSEG];
    int ch = blockIdx.x, t = threadIdx.x;
    h[t] = 0; h[t + 256] = 0;
    __syncthreads();
    int i = ch * 256 + t;
    if (i < m) atomicAdd(&h[sptids[i]], 1);
    __syncthreads();
    chunkhist[ch * NSEG + t] = h[t];
    chunkhist[ch * NSEG + t + 256] = h[t + 256];
}

// K5: one block, 512 threads. totals -> exclusive scan over segments -> per-chunk offsets
// chunkoff[0*NSEG+s] is also the segment-s base in sorted order (used by seg_final).
__global__ __launch_bounds__(NSEG)
void seg_offsets(const int* __restrict__ chunkhist, int* __restrict__ chunkoff, int nch) {
    __shared__ int tot[NSEG];
    int s = threadIdx.x;
    int sum = 0;
    for (int c = 0; c < nch; c++) sum += chunkhist[c * NSEG + s];
    tot[s] = sum;
    __syncthreads();
    int incl = sum;
    for (int off = 1; off < NSEG; off <<= 1) {
        int add = (s >= off) ? tot[s - off] : 0;
        __syncthreads();
        incl += add;
        tot[s] = incl;
        __syncthreads();
    }
    int running = incl - sum;  // exclusive base for this segment
    for (int c = 0; c < nch; c++) {
        chunkoff[c * NSEG + s] = running;
        running += chunkhist[c * NSEG + s];
    }
}

// K6: stable scatter (counting sort) of d_points; also emit sorted_nn / sorted_orig
// so the segment pass only touches its own members.
__global__ __launch_bounds__(256)
void scatter_out(const float* __restrict__ dpts, const int* __restrict__ sptids,
                 const int* __restrict__ chunkoff, const int* __restrict__ nn_idx,
                 float* __restrict__ out, int* __restrict__ sorted_nn,
                 int* __restrict__ sorted_orig, int m) {
    __shared__ int segs[256];
    int ch = blockIdx.x, t = threadIdx.x;
    int i = ch * 256 + t;
    int seg = (i < m) ? sptids[i] : -1;
    segs[t] = seg;
    __syncthreads();
    if (i >= m) return;
    int rank = 0;
    for (int j = 0; j < t; j++) rank += (segs[j] == seg) ? 1 : 0;  // stable within chunk
    int pos = chunkoff[ch * NSEG + seg] + rank;
    out[(size_t)pos * 3 + 0] = dpts[(size_t)i * 3 + 0];
    out[(size_t)pos * 3 + 1] = dpts[(size_t)i * 3 + 1];
    out[(size_t)pos * 3 + 2] = dpts[(size_t)i * 3 + 2];
    sorted_nn[pos] = nn_idx[i];
    sorted_orig[pos] = i;
}

// K7: one wave per segment: f64 sum of gathered scores over the segment's
// contiguous sorted range, argmax (strict > : first max wins), write labels
// back to original positions. argmax(sum) == argmax(mean).
__global__ __launch_bounds__(64)
void seg_final(const int* __restrict__ chunkoff, const int* __restrict__ sorted_nn,
               const int* __restrict__ sorted_orig, const float* __restrict__ scores,
               float* __restrict__ out, int m) {
    int s = blockIdx.x, lane = threadIdx.x;
    int base = chunkoff[s];                       // chunk-0 offset == segment base
    int end  = (s == NSEG - 1) ? m : chunkoff[s + 1];
    double acc[C];
#pragma unroll
    for (int c = 0; c < C; c++) acc[c] = 0.0;
    for (int j = base + lane; j < end; j += 64) {
        const float* sp = scores + (size_t)sorted_nn[j] * C;
#pragma unroll
        for (int c = 0; c < C; c++) acc[c] += (double)sp[c];
    }
#pragma unroll
    for (int c = 0; c < C; c++) {
        for (int off = 32; off; off >>= 1) acc[c] += __shfl_down(acc[c], off, 64);
    }
    int best = 0;
    if (lane == 0) {
        double bv = acc[0];
        for (int c = 1; c < C; c++)
            if (acc[c] > bv) { bv = acc[c]; best = c; }
    }
    best = __shfl(best, 0, 64);
    float fb = (float)best;
    for (int j = base + lane; j < end; j += 64)
        out[(size_t)m * 3 + sorted_orig[j]] = fb;
}

extern "C" void kernel_launch(void* const* d_in, const int* in_sizes, int n_in,
                              void* d_out, int out_size, void* d_ws, size_t ws_size,
                              hipStream_t stream) {
    const float* points = (const float*)d_in[0];
    const float* scores = (const float*)d_in[1];
    const float* dpts   = (const float*)d_in[2];
    const int*   sptids = (const int*)d_in[3];

    int n = in_sizes[0] / 3;
    int m = in_sizes[2] / 3;
    int PC  = (n + PPB - 1) / PPB;     // 64 point chunks
    int QC  = (m + QPB - 1) / QPB;     // 8 query chunks
    int NCH = (m + 255) / 256;         // 64 chunks for counting sort

    char* ws = (char*)d_ws;
    float4* pts4       = (float4*)ws;  ws += (size_t)n * sizeof(float4);
    float*  pbv        = (float*)ws;   ws += (size_t)PC * m * sizeof(float);
    float*  gmin       = (float*)ws;   ws += (size_t)m * sizeof(float);
    int*    nn_idx     = (int*)ws;     ws += (size_t)m * sizeof(int);
    int*    flagged    = (int*)ws;     ws += (size_t)m * sizeof(int);
    int*    nflag      = (int*)ws;     ws += 64;   // keep alignment
    int*    chunkhist  = (int*)ws;     ws += (size_t)NCH * NSEG * sizeof(int);
    int*    chunkoff   = (int*)ws;     ws += (size_t)NCH * NSEG * sizeof(int);
    int*    sorted_nn  = (int*)ws;     ws += (size_t)m * sizeof(int);
    int*    sorted_orig= (int*)ws;     ws += (size_t)m * sizeof(int);

    prep_pts4<<<(n + 255) / 256, 256, 0, stream>>>(points, pts4, n, nflag);
    nn_partial<<<dim3(QC, PC), K1_THREADS, 0, stream>>>(pts4, dpts, n, m, pbv);
    nn_merge<<<(m + 3) / 4, 256, 0, stream>>>(pts4, dpts, pbv, n, m, PC,
                                              gmin, nn_idx, flagged, nflag);
    nn_refine<<<1024, 256, 0, stream>>>(pts4, dpts, flagged, nflag, gmin, pbv,
                                        n, m, PC, nn_idx);
    chunk_hist<<<NCH, 256, 0, stream>>>(sptids, chunkhist, m);
    seg_offsets<<<1, NSEG, 0, stream>>>(chunkhist, chunkoff, NCH);
    scatter_out<<<NCH, 256, 0, stream>>>(dpts, sptids, chunkoff, nn_idx,
                                         (float*)d_out, sorted_nn, sorted_orig, m);
    seg_final<<<NSEG, 64, 0, stream>>>(chunkoff, sorted_nn, sorted_orig, scores,
                                       (float*)d_out, m);
}

// Round 6
// 99.277 us; speedup vs baseline: 2.4750x; 1.0270x over previous
//
#include <hip/hip_runtime.h>
#include <cfloat>
#include <cstdint>

#define NSEG 512
#define C 21

#define PPB 512                   // points per chunk
#define PCMAX 64                  // n/PPB
#define EPS_PICK 1e-3f            // >= 2*deltaM (MFMA emu error <=2e-4 worst) and >= deltaM+delta32

typedef short short8 __attribute__((ext_vector_type(8)));     // 8 bf16 (MFMA A/B frag)
typedef float f32x4 __attribute__((ext_vector_type(4)));      // MFMA acc

// truncate r to bf16 (exact split: hi has a's top bits, r -= hi is exact in f32)
__device__ inline unsigned short bsplit(float& r) {
    unsigned int u = __float_as_uint(r) & 0xFFFF0000u;
    r -= __uint_as_float(u);
    return (unsigned short)(u >> 16);
}

// K0: three duties.
//  all 128 blocks : point i -> pts4 (f32 filter data) + ptsplit (A-side bf16 slots, frag-major)
//  blocks  0..63  : query q -> qsplit (B-side bf16 slots, frag-major)
//  blocks 64..127 : 256-chunk histogram of sptids
// K-slot layout (K=32, 21 used), per coord c (a=-2*p_c, b=q_c):
//   slots 6c..6c+5: A=[ah,ah,al,al,ah,a2]  B=[bh,bl,bh,bl,b2,bh]
//   slots 18..20:   A=[s0,s1,s2] (|p|^2 split)  B=[1,1,1];  slots 21..31: 0
__global__ __launch_bounds__(256)
void prep(const float* __restrict__ pts, const float* __restrict__ dpts,
          const int* __restrict__ sptids, int n, int m,
          float4* __restrict__ pts4, short8* __restrict__ ptsplit,
          short8* __restrict__ qsplit, int* __restrict__ chunkhist) {
    __shared__ int h[NSEG];
    int bid = blockIdx.x, t = threadIdx.x;

    int i = bid * 256 + t;
    if (i < n) {
        float x = pts[i * 3 + 0], y = pts[i * 3 + 1], z = pts[i * 3 + 2];
        pts4[i] = make_float4(x, y, z, fmaf(x, x, fmaf(y, y, z * z)));
        unsigned short sl[24];
#pragma unroll
        for (int c = 0; c < 3; c++) {
            float a = -2.f * ((c == 0) ? x : (c == 1) ? y : z);   // exact in f32
            float r = a;
            unsigned short ah = bsplit(r), al = bsplit(r), a2 = bsplit(r);
            sl[c * 6 + 0] = ah; sl[c * 6 + 1] = ah; sl[c * 6 + 2] = al;
            sl[c * 6 + 3] = al; sl[c * 6 + 4] = ah; sl[c * 6 + 5] = a2;
        }
        double pr = (double)x * x + (double)y * y + (double)z * z;
#pragma unroll
        for (int l = 0; l < 3; l++) {                             // |p|^2 hi/lo/lo2
            float f = (float)pr;
            unsigned int u = __float_as_uint(f) & 0xFFFF0000u;
            pr -= (double)__uint_as_float(u);
            sl[18 + l] = (unsigned short)(u >> 16);
        }
        sl[21] = 0; sl[22] = 0; sl[23] = 0;
        size_t base = (size_t)(i >> 4) * 64 + (i & 15);           // frag-major: tile*64 + s*16 + row
        short8 g0, g1, g2, gz;
#pragma unroll
        for (int j = 0; j < 8; j++) { g0[j] = (short)sl[j]; g1[j] = (short)sl[8 + j]; g2[j] = (short)sl[16 + j]; gz[j] = 0; }
        ptsplit[base + 0] = g0; ptsplit[base + 16] = g1;
        ptsplit[base + 32] = g2; ptsplit[base + 48] = gz;
    }

    if (bid < 64) {               // query split
        int q = bid * 256 + t;
        if (q < m) {
            unsigned short sl[24];
#pragma unroll
            for (int c = 0; c < 3; c++) {
                float b = dpts[q * 3 + c];
                float r = b;
                unsigned short bh = bsplit(r), bl = bsplit(r), b2 = bsplit(r);
                sl[c * 6 + 0] = bh; sl[c * 6 + 1] = bl; sl[c * 6 + 2] = bh;
                sl[c * 6 + 3] = bl; sl[c * 6 + 4] = b2; sl[c * 6 + 5] = bh;
            }
            sl[18] = 0x3F80; sl[19] = 0x3F80; sl[20] = 0x3F80;    // bf16 1.0
            sl[21] = 0; sl[22] = 0; sl[23] = 0;
            size_t base = (size_t)(q >> 4) * 64 + (q & 15);
            short8 g0, g1, g2, gz;
#pragma unroll
            for (int j = 0; j < 8; j++) { g0[j] = (short)sl[j]; g1[j] = (short)sl[8 + j]; g2[j] = (short)sl[16 + j]; gz[j] = 0; }
            qsplit[base + 0] = g0; qsplit[base + 16] = g1;
            qsplit[base + 32] = g2; qsplit[base + 48] = gz;
        }
    } else {                      // histogram chunk (bid-64)
        int ch = bid - 64;
        h[t] = 0; h[t + 256] = 0;
        __syncthreads();
        int j = ch * 256 + t;
        if (j < m) atomicAdd(&h[sptids[j]], 1);
        __syncthreads();
        chunkhist[ch * NSEG + t] = h[t];
        chunkhist[ch * NSEG + t + 256] = h[t + 256];
    }
}

// K1: emulated-f32 distance matmul on the MATRIX pipe + per-chunk min.
// Block = 8 waves x 128 queries = 1024 queries, 4 chunks of 512 points.
// Per wave: 8 resident B-frags; per A-frag (16 points): 8 MFMAs + 16 v_min3.
// D layout (verified): col=lane&15 (query), row=(lane>>4)*4+reg (point, minned away).
__global__ __launch_bounds__(512)
void nn_mfma(const short8* __restrict__ ptsplit, const short8* __restrict__ qsplit,
             float* __restrict__ pbv, int m) {
    __shared__ short8 abuf[2048];                 // 32 KB: one 512-pt chunk, frag-major
    int t = threadIdx.x;
    int wave = t >> 6, lane = t & 63;
    int qb = blockIdx.x;                          // 16 blocks of 1024 queries
    int cg = blockIdx.y;                          // 16 groups of 4 chunks

    short8 bq[8];
    int qtbase = qb * 64 + wave * 8;
#pragma unroll
    for (int f = 0; f < 8; f++) bq[f] = qsplit[(size_t)(qtbase + f) * 64 + lane];

    const float4* psrc = (const float4*)ptsplit;
    float4* lbuf = (float4*)abuf;
    int c0 = cg * 4;
    float4 st0, st1, st2, st3;
    st0 = psrc[(size_t)c0 * 2048 + 0 * 512 + t];
    st1 = psrc[(size_t)c0 * 2048 + 1 * 512 + t];
    st2 = psrc[(size_t)c0 * 2048 + 2 * 512 + t];
    st3 = psrc[(size_t)c0 * 2048 + 3 * 512 + t];
    lbuf[0 * 512 + t] = st0; lbuf[1 * 512 + t] = st1;
    lbuf[2 * 512 + t] = st2; lbuf[3 * 512 + t] = st3;
    __syncthreads();

    for (int cl = 0; cl < 4; cl++) {
        int pc = c0 + cl;
        if (cl < 3) {                             // issue next-chunk loads early (hide HBM/L2)
            st0 = psrc[(size_t)(pc + 1) * 2048 + 0 * 512 + t];
            st1 = psrc[(size_t)(pc + 1) * 2048 + 1 * 512 + t];
            st2 = psrc[(size_t)(pc + 1) * 2048 + 2 * 512 + t];
            st3 = psrc[(size_t)(pc + 1) * 2048 + 3 * 512 + t];
        }
        float run[8];
#pragma unroll
        for (int f = 0; f < 8; f++) run[f] = FLT_MAX;
        f32x4 zero = {0.f, 0.f, 0.f, 0.f};
#pragma unroll 4
        for (int tt = 0; tt < 32; tt++) {
            short8 a = abuf[tt * 64 + lane];      // lane-contiguous b128: conflict-free
#pragma unroll
            for (int f = 0; f < 8; f++) {
                f32x4 acc = __builtin_amdgcn_mfma_f32_16x16x32_bf16(a, bq[f], zero, 0, 0, 0);
                float t1 = fminf(fminf(acc[0], acc[1]), acc[2]);          // v_min3
                run[f] = fminf(fminf(t1, acc[3]), run[f]);                // v_min3
            }
        }
#pragma unroll
        for (int f = 0; f < 8; f++) {             // merge the 4 row-groups, write chunk min
            float v = run[f];
            v = fminf(v, __shfl_xor(v, 16, 64));
            v = fminf(v, __shfl_xor(v, 32, 64));
            if (lane < 16)
                pbv[(size_t)pc * m + qb * 1024 + wave * 128 + f * 16 + lane] = v;
        }
        __syncthreads();                          // all waves done reading abuf
        if (cl < 3) {
            lbuf[0 * 512 + t] = st0; lbuf[1 * 512 + t] = st1;
            lbuf[2 * 512 + t] = st2; lbuf[3 * 512 + t] = st3;
            __syncthreads();
        }
    }
}

// K2: thread-per-query global min + qualifying-chunk mask (coalesced, LDS-tiled).
__global__ __launch_bounds__(256)
void nn_gmin(const float* __restrict__ pbv, int m,
             float* __restrict__ gmin, unsigned long long* __restrict__ qmask) {
    __shared__ float lt[PCMAX][256];              // 64 KB
    int t = threadIdx.x, qbase = blockIdx.x * 256;
    for (int pc = 0; pc < PCMAX; pc++) lt[pc][t] = pbv[(size_t)pc * m + qbase + t];
    __syncthreads();
    float g1 = FLT_MAX;
#pragma unroll 8
    for (int pc = 0; pc < PCMAX; pc++) g1 = fminf(g1, lt[pc][t]);
    float thr = g1 + EPS_PICK;
    unsigned long long msk = 0;
#pragma unroll 8
    for (int pc = 0; pc < PCMAX; pc++)
        if (lt[pc][t] <= thr) msk |= 1ull << pc;
    gmin[qbase + t] = g1;
    qmask[qbase + t] = msk;
}

// K3: wave-per-query exact resolution. Scan only qualifying chunks (typ. 1-2);
// f32 filter (v32 <= g1+EPS covers deltaM+delta32); exact f64 eval on survivors;
// lowest-index tie-break == full f64 argmin semantics (validated R1-R5).
__global__ __launch_bounds__(256)
void nn_pick(const float4* __restrict__ pts4, const float* __restrict__ dpts,
             const float* __restrict__ gmin, const unsigned long long* __restrict__ qmask,
             int n, int m, int* __restrict__ nn_idx) {
    int wid = threadIdx.x >> 6, lane = threadIdx.x & 63;
    for (int q = blockIdx.x * 4 + wid; q < m; q += gridDim.x * 4) {
        float g1 = gmin[q];
        unsigned long long msk = qmask[q];
        float thr = g1 + EPS_PICK;
        float fx = dpts[q * 3 + 0], fy = dpts[q * 3 + 1], fz = dpts[q * 3 + 2];
        float fm2x = -2.f * fx, fm2y = -2.f * fy, fm2z = -2.f * fz;
        double m2x = -2.0 * (double)fx, m2y = -2.0 * (double)fy, m2z = -2.0 * (double)fz;
        double best = 1e308; int bi = 0x7fffffff;
        while (msk) {
            int pc = __builtin_ctzll(msk); msk &= msk - 1;
            int base = pc * PPB + lane;
#pragma unroll
            for (int r2 = 0; r2 < PPB / 64; r2++) {
                int i = base + r2 * 64;
                if (i < n) {
                    float4 p = pts4[i];
                    float v = fmaf(p.x, fm2x, fmaf(p.y, fm2y, fmaf(p.z, fm2z, p.w)));
                    if (v <= thr) {
                        double ps = (double)p.x * p.x + (double)p.y * p.y + (double)p.z * p.z;
                        double dv = fma((double)p.x, m2x, fma((double)p.y, m2y,
                                    fma((double)p.z, m2z, ps)));
                        if (dv < best || (dv == best && i < bi)) { best = dv; bi = i; }
                    }
                }
            }
        }
#pragma unroll
        for (int off = 32; off; off >>= 1) {
            double ov = __shfl_down(best, off, 64);
            int oi = __shfl_down(bi, off, 64);
            if (ov < best || (ov == best && oi < bi)) { best = ov; bi = oi; }
        }
        if (lane == 0) nn_idx[q] = bi;
    }
}

// K4: one block: totals -> exclusive scan -> per-chunk offsets (chunkoff[0][s] = segment base)
__global__ __launch_bounds__(NSEG)
void seg_offsets(const int* __restrict__ chunkhist, int* __restrict__ chunkoff, int nch) {
    __shared__ int tot[NSEG];
    int s = threadIdx.x;
    int sum = 0;
    for (int c = 0; c < nch; c++) sum += chunkhist[c * NSEG + s];
    tot[s] = sum;
    __syncthreads();
    int incl = sum;
    for (int off = 1; off < NSEG; off <<= 1) {
        int add = (s >= off) ? tot[s - off] : 0;
        __syncthreads();
        incl += add;
        tot[s] = incl;
        __syncthreads();
    }
    int running = incl - sum;
    for (int c = 0; c < nch; c++) {
        chunkoff[c * NSEG + s] = running;
        running += chunkhist[c * NSEG + s];
    }
}

// K5: stable counting-sort scatter of d_points; emit sorted_nn / sorted_orig
__global__ __launch_bounds__(256)
void scatter_out(const float* __restrict__ dpts, const int* __restrict__ sptids,
                 const int* __restrict__ chunkoff, const int* __restrict__ nn_idx,
                 float* __restrict__ out, int* __restrict__ sorted_nn,
                 int* __restrict__ sorted_orig, int m) {
    __shared__ int segs[256];
    int ch = blockIdx.x, t = threadIdx.x;
    int i = ch * 256 + t;
    int seg = (i < m) ? sptids[i] : -1;
    segs[t] = seg;
    __syncthreads();
    if (i >= m) return;
    int rank = 0;
    for (int j = 0; j < t; j++) rank += (segs[j] == seg) ? 1 : 0;
    int pos = chunkoff[ch * NSEG + seg] + rank;
    out[(size_t)pos * 3 + 0] = dpts[(size_t)i * 3 + 0];
    out[(size_t)pos * 3 + 1] = dpts[(size_t)i * 3 + 1];
    out[(size_t)pos * 3 + 2] = dpts[(size_t)i * 3 + 2];
    sorted_nn[pos] = nn_idx[i];
    sorted_orig[pos] = i;
}

// K6: one wave per segment: f64 score sum over the segment's sorted range,
// argmax (strict >), write labels to original positions. argmax(sum)==argmax(mean).
__global__ __launch_bounds__(64)
void seg_final(const int* __restrict__ chunkoff, const int* __restrict__ sorted_nn,
               const int* __restrict__ sorted_orig, const float* __restrict__ scores,
               float* __restrict__ out, int m) {
    int s = blockIdx.x, lane = threadIdx.x;
    int base = chunkoff[s];
    int end  = (s == NSEG - 1) ? m : chunkoff[s + 1];
    double acc[C];
#pragma unroll
    for (int c = 0; c < C; c++) acc[c] = 0.0;
    for (int j = base + lane; j < end; j += 64) {
        const float* sp = scores + (size_t)sorted_nn[j] * C;
#pragma unroll
        for (int c = 0; c < C; c++) acc[c] += (double)sp[c];
    }
#pragma unroll
    for (int c = 0; c < C; c++) {
        for (int off = 32; off; off >>= 1) acc[c] += __shfl_down(acc[c], off, 64);
    }
    int best = 0;
    if (lane == 0) {
        double bv = acc[0];
        for (int c = 1; c < C; c++)
            if (acc[c] > bv) { bv = acc[c]; best = c; }
    }
    best = __shfl(best, 0, 64);
    float fb = (float)best;
    for (int j = base + lane; j < end; j += 64)
        out[(size_t)m * 3 + sorted_orig[j]] = fb;
}

extern "C" void kernel_launch(void* const* d_in, const int* in_sizes, int n_in,
                              void* d_out, int out_size, void* d_ws, size_t ws_size,
                              hipStream_t stream) {
    const float* points = (const float*)d_in[0];
    const float* scores = (const float*)d_in[1];
    const float* dpts   = (const float*)d_in[2];
    const int*   sptids = (const int*)d_in[3];

    int n = in_sizes[0] / 3;          // 32768
    int m = in_sizes[2] / 3;          // 16384
    int PC  = (n + PPB - 1) / PPB;    // 64
    int NCH = (m + 255) / 256;        // 64

    char* ws = (char*)d_ws;
    short8* ptsplit    = (short8*)ws;  ws += (size_t)n * 64;            // frag-major bf16 slots
    short8* qsplit     = (short8*)ws;  ws += (size_t)m * 64;
    float4* pts4       = (float4*)ws;  ws += (size_t)n * sizeof(float4);
    float*  pbv        = (float*)ws;   ws += (size_t)PC * m * sizeof(float);
    float*  gmin       = (float*)ws;   ws += (size_t)m * sizeof(float);
    unsigned long long* qmask = (unsigned long long*)ws; ws += (size_t)m * 8;
    int*    nn_idx     = (int*)ws;     ws += (size_t)m * sizeof(int);
    int*    chunkhist  = (int*)ws;     ws += (size_t)NCH * NSEG * sizeof(int);
    int*    chunkoff   = (int*)ws;     ws += (size_t)NCH * NSEG * sizeof(int);
    int*    sorted_nn  = (int*)ws;     ws += (size_t)m * sizeof(int);
    int*    sorted_orig= (int*)ws;     ws += (size_t)m * sizeof(int);

    prep<<<128, 256, 0, stream>>>(points, dpts, sptids, n, m,
                                  pts4, ptsplit, qsplit, chunkhist);
    nn_mfma<<<dim3(16, 16), 512, 0, stream>>>(ptsplit, qsplit, pbv, m);
    nn_gmin<<<64, 256, 0, stream>>>(pbv, m, gmin, qmask);
    nn_pick<<<1024, 256, 0, stream>>>(pts4, dpts, gmin, qmask, n, m, nn_idx);
    seg_offsets<<<1, NSEG, 0, stream>>>(chunkhist, chunkoff, NCH);
    scatter_out<<<NCH, 256, 0, stream>>>(dpts, sptids, chunkoff, nn_idx,
                                         (float*)d_out, sorted_nn, sorted_orig, m);
    seg_final<<<NSEG, 64, 0, stream>>>(chunkoff, sorted_nn, sorted_orig, scores,
                                       (float*)d_out, m);
}

// Round 7
// 77.011 us; speedup vs baseline: 3.1906x; 1.2891x over previous
//
#include <hip/hip_runtime.h>
#include <cfloat>
#include <cstdint>

#define NSEG 512
#define C 21

#define PPB 512                   // points per chunk
#define PCMAX 64                  // n/PPB (= 64 = one chunk per lane in pick)
#define EPS_PICK 1e-3f            // >= 2*deltaM (MFMA emu) and >= deltaM+delta32 (filter)

typedef short short8 __attribute__((ext_vector_type(8)));     // 8 bf16 (MFMA A/B frag)
typedef float f32x4 __attribute__((ext_vector_type(4)));      // MFMA acc

// truncate r to bf16 (exact split: hi takes the top bits, r -= hi exact in f32)
__device__ inline unsigned short bsplit(float& r) {
    unsigned int u = __float_as_uint(r) & 0xFFFF0000u;
    r -= __uint_as_float(u);
    return (unsigned short)(u >> 16);
}

// K0: three duties.
//  all 128 blocks : point i -> pts4 (f32 filter data) + ptsplit (A-side bf16 slots, frag-major)
//  blocks  0..63  : query q -> qsplit (B-side bf16 slots, frag-major)
//  blocks 64..127 : 256-chunk histogram of sptids -> chunkhistT[seg][ch]
// K-slot layout (K=32, 21 used), per coord c (a=-2*p_c, b=q_c):
//   slots 6c..6c+5: A=[ah,ah,al,al,ah,a2]  B=[bh,bl,bh,bl,b2,bh]
//   slots 18..20:   A=[s0,s1,s2] (|p|^2 split)  B=[1,1,1];  slots 21..31: 0
__global__ __launch_bounds__(256)
void prep(const float* __restrict__ pts, const float* __restrict__ dpts,
          const int* __restrict__ sptids, int n, int m,
          float4* __restrict__ pts4, short8* __restrict__ ptsplit,
          short8* __restrict__ qsplit, int* __restrict__ chunkhistT) {
    __shared__ int h[NSEG];
    int bid = blockIdx.x, t = threadIdx.x;

    int i = bid * 256 + t;
    if (i < n) {
        float x = pts[i * 3 + 0], y = pts[i * 3 + 1], z = pts[i * 3 + 2];
        pts4[i] = make_float4(x, y, z, fmaf(x, x, fmaf(y, y, z * z)));
        unsigned short sl[24];
#pragma unroll
        for (int c = 0; c < 3; c++) {
            float a = -2.f * ((c == 0) ? x : (c == 1) ? y : z);   // exact in f32
            float r = a;
            unsigned short ah = bsplit(r), al = bsplit(r), a2 = bsplit(r);
            sl[c * 6 + 0] = ah; sl[c * 6 + 1] = ah; sl[c * 6 + 2] = al;
            sl[c * 6 + 3] = al; sl[c * 6 + 4] = ah; sl[c * 6 + 5] = a2;
        }
        double pr = (double)x * x + (double)y * y + (double)z * z;
#pragma unroll
        for (int l = 0; l < 3; l++) {                             // |p|^2 hi/lo/lo2
            float f = (float)pr;
            unsigned int u = __float_as_uint(f) & 0xFFFF0000u;
            pr -= (double)__uint_as_float(u);
            sl[18 + l] = (unsigned short)(u >> 16);
        }
        sl[21] = 0; sl[22] = 0; sl[23] = 0;
        size_t base = (size_t)(i >> 4) * 64 + (i & 15);           // frag-major: tile*64 + s*16 + row
        short8 g0, g1, g2, gz;
#pragma unroll
        for (int j = 0; j < 8; j++) { g0[j] = (short)sl[j]; g1[j] = (short)sl[8 + j]; g2[j] = (short)sl[16 + j]; gz[j] = 0; }
        ptsplit[base + 0] = g0; ptsplit[base + 16] = g1;
        ptsplit[base + 32] = g2; ptsplit[base + 48] = gz;
    }

    if (bid < 64) {               // query split
        int q = bid * 256 + t;
        if (q < m) {
            unsigned short sl[24];
#pragma unroll
            for (int c = 0; c < 3; c++) {
                float b = dpts[q * 3 + c];
                float r = b;
                unsigned short bh = bsplit(r), bl = bsplit(r), b2 = bsplit(r);
                sl[c * 6 + 0] = bh; sl[c * 6 + 1] = bl; sl[c * 6 + 2] = bh;
                sl[c * 6 + 3] = bl; sl[c * 6 + 4] = b2; sl[c * 6 + 5] = bh;
            }
            sl[18] = 0x3F80; sl[19] = 0x3F80; sl[20] = 0x3F80;    // bf16 1.0
            sl[21] = 0; sl[22] = 0; sl[23] = 0;
            size_t base = (size_t)(q >> 4) * 64 + (q & 15);
            short8 g0, g1, g2, gz;
#pragma unroll
            for (int j = 0; j < 8; j++) { g0[j] = (short)sl[j]; g1[j] = (short)sl[8 + j]; g2[j] = (short)sl[16 + j]; gz[j] = 0; }
            qsplit[base + 0] = g0; qsplit[base + 16] = g1;
            qsplit[base + 32] = g2; qsplit[base + 48] = gz;
        }
    } else {                      // histogram chunk (bid-64), write transposed [seg][ch]
        int ch = bid - 64;
        h[t] = 0; h[t + 256] = 0;
        __syncthreads();
        int j = ch * 256 + t;
        if (j < m) atomicAdd(&h[sptids[j]], 1);
        __syncthreads();
        chunkhistT[t * 64 + ch] = h[t];
        chunkhistT[(t + 256) * 64 + ch] = h[t + 256];
    }
}

// K1: emulated-f32 distance matmul on the MATRIX pipe + per-chunk min.
// Block = 8 waves x 128 queries = 1024 queries, 4 chunks of 512 points.
// D layout (verified): col=lane&15 (query), row=(lane>>4)*4+reg (point, minned away).
// Writes pbvT[q][pc] (scattered 4B stores, fire-and-forget) for coalesced pick reads.
__global__ __launch_bounds__(512)
void nn_mfma(const short8* __restrict__ ptsplit, const short8* __restrict__ qsplit,
             float* __restrict__ pbvT, int m) {
    __shared__ short8 abuf[2048];                 // 32 KB: one 512-pt chunk, frag-major
    int t = threadIdx.x;
    int wave = t >> 6, lane = t & 63;
    int qb = blockIdx.x;                          // 16 blocks of 1024 queries
    int cg = blockIdx.y;                          // 16 groups of 4 chunks

    short8 bq[8];
    int qtbase = qb * 64 + wave * 8;
#pragma unroll
    for (int f = 0; f < 8; f++) bq[f] = qsplit[(size_t)(qtbase + f) * 64 + lane];

    const float4* psrc = (const float4*)ptsplit;
    float4* lbuf = (float4*)abuf;
    int c0 = cg * 4;
    float4 st0, st1, st2, st3;
    st0 = psrc[(size_t)c0 * 2048 + 0 * 512 + t];
    st1 = psrc[(size_t)c0 * 2048 + 1 * 512 + t];
    st2 = psrc[(size_t)c0 * 2048 + 2 * 512 + t];
    st3 = psrc[(size_t)c0 * 2048 + 3 * 512 + t];
    lbuf[0 * 512 + t] = st0; lbuf[1 * 512 + t] = st1;
    lbuf[2 * 512 + t] = st2; lbuf[3 * 512 + t] = st3;
    __syncthreads();

    for (int cl = 0; cl < 4; cl++) {
        int pc = c0 + cl;
        if (cl < 3) {                             // issue next-chunk loads early
            st0 = psrc[(size_t)(pc + 1) * 2048 + 0 * 512 + t];
            st1 = psrc[(size_t)(pc + 1) * 2048 + 1 * 512 + t];
            st2 = psrc[(size_t)(pc + 1) * 2048 + 2 * 512 + t];
            st3 = psrc[(size_t)(pc + 1) * 2048 + 3 * 512 + t];
        }
        float run[8];
#pragma unroll
        for (int f = 0; f < 8; f++) run[f] = FLT_MAX;
        f32x4 zero = {0.f, 0.f, 0.f, 0.f};
#pragma unroll 4
        for (int tt = 0; tt < 32; tt++) {
            short8 a = abuf[tt * 64 + lane];      // lane-contiguous b128: conflict-free
#pragma unroll
            for (int f = 0; f < 8; f++) {
                f32x4 acc = __builtin_amdgcn_mfma_f32_16x16x32_bf16(a, bq[f], zero, 0, 0, 0);
                float t1 = fminf(fminf(acc[0], acc[1]), acc[2]);          // v_min3
                run[f] = fminf(fminf(t1, acc[3]), run[f]);                // v_min3
            }
        }
#pragma unroll
        for (int f = 0; f < 8; f++) {             // merge 4 row-groups, write chunk min
            float v = run[f];
            v = fminf(v, __shfl_xor(v, 16, 64));
            v = fminf(v, __shfl_xor(v, 32, 64));
            if (lane < 16)
                pbvT[(size_t)(qb * 1024 + wave * 128 + f * 16 + lane) * 64 + pc] = v;
        }
        __syncthreads();
        if (cl < 3) {
            lbuf[0 * 512 + t] = st0; lbuf[1 * 512 + t] = st1;
            lbuf[2 * 512 + t] = st2; lbuf[3 * 512 + t] = st3;
            __syncthreads();
        }
    }
}

// K2: fused {gmin + chunk mask + exact pick} wave-per-query, PLUS the segment-offset
// scan as the last block (depends only on prep's chunkhistT -> safe, runs concurrently).
// Per wave: lane pc reads pbvT[q][pc] (coalesced 256B), butterfly min -> g1,
// ballot(v<=g1+EPS) -> qualifying-chunk mask; scan those chunks with f32 filter;
// exact f64 eval on survivors; lowest-index tie-break == full f64 argmin semantics.
__global__ __launch_bounds__(512)
void nn_pick(const float4* __restrict__ pts4, const float* __restrict__ dpts,
             const float* __restrict__ pbvT, const int* __restrict__ chunkhistT,
             int* __restrict__ chunkoffT, int n, int m, int nch,
             int* __restrict__ nn_idx) {
    if (blockIdx.x == gridDim.x - 1) {
        // ---- segment-offset scan (512 threads == NSEG) ----
        __shared__ int tot[NSEG];
        int s = threadIdx.x;
        const int4* row = (const int4*)(chunkhistT + s * 64);
        int sum = 0;
#pragma unroll
        for (int c4 = 0; c4 < 16; c4++) {
            int4 v = row[c4];
            sum += v.x + v.y + v.z + v.w;
        }
        tot[s] = sum;
        __syncthreads();
        int incl = sum;
        for (int off = 1; off < NSEG; off <<= 1) {
            int add = (s >= off) ? tot[s - off] : 0;
            __syncthreads();
            incl += add;
            tot[s] = incl;
            __syncthreads();
        }
        int running = incl - sum;                 // exclusive segment base
        int4* orow = (int4*)(chunkoffT + s * 64);
#pragma unroll
        for (int c4 = 0; c4 < 16; c4++) {
            int4 v = row[c4];
            int4 o;
            o.x = running; running += v.x;
            o.y = running; running += v.y;
            o.z = running; running += v.z;
            o.w = running; running += v.w;
            orow[c4] = o;
        }
        return;
    }

    int wid = threadIdx.x >> 6, lane = threadIdx.x & 63;
    int q = blockIdx.x * 8 + wid;
    if (q >= m) return;

    float myv = pbvT[(size_t)q * 64 + lane];      // chunk `lane` min (coalesced)
    float g1 = myv;
#pragma unroll
    for (int off = 1; off < 64; off <<= 1) g1 = fminf(g1, __shfl_xor(g1, off, 64));
    float thr = g1 + EPS_PICK;
    unsigned long long msk = __ballot(myv <= thr);   // bit pc == chunk pc qualifies

    float fx = dpts[q * 3 + 0], fy = dpts[q * 3 + 1], fz = dpts[q * 3 + 2];
    float fm2x = -2.f * fx, fm2y = -2.f * fy, fm2z = -2.f * fz;
    double m2x = -2.0 * (double)fx, m2y = -2.0 * (double)fy, m2z = -2.0 * (double)fz;
    double best = 1e308; int bi = 0x7fffffff;
    while (msk) {
        int pc = __builtin_ctzll(msk); msk &= msk - 1;
        int base = pc * PPB + lane;
#pragma unroll
        for (int r2 = 0; r2 < PPB / 64; r2++) {
            int i = base + r2 * 64;
            if (i < n) {
                float4 p = pts4[i];
                float v = fmaf(p.x, fm2x, fmaf(p.y, fm2y, fmaf(p.z, fm2z, p.w)));
                if (v <= thr) {
                    double ps = (double)p.x * p.x + (double)p.y * p.y + (double)p.z * p.z;
                    double dv = fma((double)p.x, m2x, fma((double)p.y, m2y,
                                fma((double)p.z, m2z, ps)));
                    if (dv < best || (dv == best && i < bi)) { best = dv; bi = i; }
                }
            }
        }
    }
#pragma unroll
    for (int off = 32; off; off >>= 1) {
        double ov = __shfl_down(best, off, 64);
        int oi = __shfl_down(bi, off, 64);
        if (ov < best || (ov == best && oi < bi)) { best = ov; bi = oi; }
    }
    if (lane == 0) nn_idx[q] = bi;
}

// K3: stable counting-sort scatter of d_points; emit sorted_nn / sorted_orig
__global__ __launch_bounds__(256)
void scatter_out(const float* __restrict__ dpts, const int* __restrict__ sptids,
                 const int* __restrict__ chunkoffT, const int* __restrict__ nn_idx,
                 float* __restrict__ out, int* __restrict__ sorted_nn,
                 int* __restrict__ sorted_orig, int m) {
    __shared__ int segs[256];
    int ch = blockIdx.x, t = threadIdx.x;
    int i = ch * 256 + t;
    int seg = (i < m) ? sptids[i] : -1;
    segs[t] = seg;
    __syncthreads();
    if (i >= m) return;
    int rank = 0;
    for (int j = 0; j < t; j++) rank += (segs[j] == seg) ? 1 : 0;  // stable within chunk
    int pos = chunkoffT[seg * 64 + ch] + rank;
    out[(size_t)pos * 3 + 0] = dpts[(size_t)i * 3 + 0];
    out[(size_t)pos * 3 + 1] = dpts[(size_t)i * 3 + 1];
    out[(size_t)pos * 3 + 2] = dpts[(size_t)i * 3 + 2];
    sorted_nn[pos] = nn_idx[i];
    sorted_orig[pos] = i;
}

// K4: one wave per segment: f64 score sum over the segment's sorted range,
// argmax (strict > : first max wins), write labels to original positions.
// argmax(sum) == argmax(mean) since count is a positive per-segment scalar.
__global__ __launch_bounds__(64)
void seg_final(const int* __restrict__ chunkoffT, const int* __restrict__ sorted_nn,
               const int* __restrict__ sorted_orig, const float* __restrict__ scores,
               float* __restrict__ out, int m) {
    int s = blockIdx.x, lane = threadIdx.x;
    int base = chunkoffT[s * 64];                 // chunk-0 offset == segment base
    int end  = (s == NSEG - 1) ? m : chunkoffT[(s + 1) * 64];
    double acc[C];
#pragma unroll
    for (int c = 0; c < C; c++) acc[c] = 0.0;
    for (int j = base + lane; j < end; j += 64) {
        const float* sp = scores + (size_t)sorted_nn[j] * C;
#pragma unroll
        for (int c = 0; c < C; c++) acc[c] += (double)sp[c];
    }
#pragma unroll
    for (int c = 0; c < C; c++) {
        for (int off = 32; off; off >>= 1) acc[c] += __shfl_down(acc[c], off, 64);
    }
    int best = 0;
    if (lane == 0) {
        double bv = acc[0];
        for (int c = 1; c < C; c++)
            if (acc[c] > bv) { bv = acc[c]; best = c; }
    }
    best = __shfl(best, 0, 64);
    float fb = (float)best;
    for (int j = base + lane; j < end; j += 64)
        out[(size_t)m * 3 + sorted_orig[j]] = fb;
}

extern "C" void kernel_launch(void* const* d_in, const int* in_sizes, int n_in,
                              void* d_out, int out_size, void* d_ws, size_t ws_size,
                              hipStream_t stream) {
    const float* points = (const float*)d_in[0];
    const float* scores = (const float*)d_in[1];
    const float* dpts   = (const float*)d_in[2];
    const int*   sptids = (const int*)d_in[3];

    int n = in_sizes[0] / 3;          // 32768
    int m = in_sizes[2] / 3;          // 16384
    int NCH = (m + 255) / 256;        // 64

    char* ws = (char*)d_ws;
    short8* ptsplit    = (short8*)ws;  ws += (size_t)n * 64;            // frag-major bf16 slots
    short8* qsplit     = (short8*)ws;  ws += (size_t)m * 64;
    float4* pts4       = (float4*)ws;  ws += (size_t)n * sizeof(float4);
    float*  pbvT       = (float*)ws;   ws += (size_t)m * PCMAX * sizeof(float);
    int*    nn_idx     = (int*)ws;     ws += (size_t)m * sizeof(int);
    int*    chunkhistT = (int*)ws;     ws += (size_t)NSEG * 64 * sizeof(int);
    int*    chunkoffT  = (int*)ws;     ws += (size_t)NSEG * 64 * sizeof(int);
    int*    sorted_nn  = (int*)ws;     ws += (size_t)m * sizeof(int);
    int*    sorted_orig= (int*)ws;     ws += (size_t)m * sizeof(int);

    int pick_blocks = (m + 7) / 8;    // 2048 wave-per-query blocks
    prep<<<128, 256, 0, stream>>>(points, dpts, sptids, n, m,
                                  pts4, ptsplit, qsplit, chunkhistT);
    nn_mfma<<<dim3(16, 16), 512, 0, stream>>>(ptsplit, qsplit, pbvT, m);
    nn_pick<<<pick_blocks + 1, 512, 0, stream>>>(pts4, dpts, pbvT, chunkhistT,
                                                 chunkoffT, n, m, NCH, nn_idx);
    scatter_out<<<NCH, 256, 0, stream>>>(dpts, sptids, chunkoffT, nn_idx,
                                         (float*)d_out, sorted_nn, sorted_orig, m);
    seg_final<<<NSEG, 64, 0, stream>>>(chunkoffT, sorted_nn, sorted_orig, scores,
                                       (float*)d_out, m);
}